// Round 1
// baseline (151.662 us; speedup 1.0000x reference)
//
#include <hip/hip_runtime.h>

// Problem constants
#define BB 32
#define SS 50
#define DD 4
#define HH 128
#define EE 128
#define NI 5000
#define DH 512   // D*H

// ---------------------------------------------------------------------------
// K1: per-8-row gather + hidden GEMM. rows r: emb = emb_table[idx[r]],
// hidden[r][j] = sum_e emb[e] * W_demand[j*E+e].  Also writes emb rows to out.
// ---------------------------------------------------------------------------
__global__ void k_hidden(const int* __restrict__ idx, const float* __restrict__ et,
                         const float* __restrict__ Wd, float* __restrict__ emb_out,
                         float* __restrict__ hidden, int nrows) {
    int r0 = blockIdx.x * 8;
    __shared__ float se[8][EE];
    int t = threadIdx.x;
    for (int x = t; x < 8 * EE; x += 256) {
        int rr = x >> 7, e = x & 127;
        int r = r0 + rr;
        float v = 0.f;
        if (r < nrows) { v = et[idx[r] * EE + e]; emb_out[r * EE + e] = v; }
        se[rr][e] = v;
    }
    __syncthreads();
    for (int j = t; j < DH; j += 256) {
        const float* w = Wd + j * EE;
        float acc[8] = {0.f,0.f,0.f,0.f,0.f,0.f,0.f,0.f};
        for (int e = 0; e < EE; ++e) {
            float wv = w[e];
#pragma unroll
            for (int rr = 0; rr < 8; ++rr) acc[rr] += se[rr][e] * wv;
        }
#pragma unroll
        for (int rr = 0; rr < 8; ++rr) {
            int r = r0 + rr;
            if (r < nrows) hidden[r * DH + j] = acc[rr];
        }
    }
}

// ---------------------------------------------------------------------------
// K2: agg[b][d*H+h] = log(sum_s exp(hidden[(b*S+s)][d*H+h]))   (16384 outputs)
// ---------------------------------------------------------------------------
__global__ void k_agg(const float* __restrict__ hidden, float* __restrict__ agg) {
    int t = blockIdx.x * 256 + threadIdx.x;   // 0..16383
    int b = t >> 9, j = t & 511;
    float s = 0.f;
    for (int si = 0; si < SS; ++si) s += expf(hidden[(b * SS + si) * DH + j]);
    agg[t] = logf(s);
}

// ---------------------------------------------------------------------------
// K3: demand_sim_loss. 128 threads: norms per (b,d); then per-b off-diag sum.
// sum_{d!=e} u_d.u_e = ||sum_d u_d||^2 - sum_d ||u_d||^2
// ---------------------------------------------------------------------------
__global__ void k_loss(const float* __restrict__ agg, float* __restrict__ loss_out) {
    __shared__ float nrm[BB * DD];
    int t = threadIdx.x;  // blockDim = 128
    if (t < BB * DD) {
        const float* a = agg + t * HH;
        float s = 0.f;
        for (int h = 0; h < HH; ++h) s += a[h] * a[h];
        nrm[t] = fmaxf(sqrtf(s), 1e-8f);
    }
    __syncthreads();
    float lb = 0.f;
    if (t < BB) {
        const float* a = agg + t * DH;
        float i0 = 1.f / nrm[t*4+0], i1 = 1.f / nrm[t*4+1];
        float i2 = 1.f / nrm[t*4+2], i3 = 1.f / nrm[t*4+3];
        for (int h = 0; h < HH; ++h) {
            float u0 = a[h] * i0, u1 = a[HH + h] * i1;
            float u2 = a[2*HH + h] * i2, u3 = a[3*HH + h] * i3;
            float v = u0 + u1 + u2 + u3;
            lb += v * v - (u0*u0 + u1*u1 + u2*u2 + u3*u3);
        }
    }
    // reduce across wave 0 (threads >=32 contribute 0)
    for (int off = 32; off; off >>= 1) lb += __shfl_down(lb, off);
    if (t == 0) loss_out[0] = lb / (float)(BB * DD * (DD - 1));
}

// ---------------------------------------------------------------------------
// K4: agg_proj[bd][o] = b_score[o] + sum_h agg[bd][h] * W_score[o*256+h]
// ---------------------------------------------------------------------------
__global__ void k_aggproj(const float* __restrict__ agg, const float* __restrict__ Ws,
                          const float* __restrict__ bsc, float* __restrict__ ap) {
    int t = blockIdx.x * 256 + threadIdx.x;  // 0..16383
    int bd = t >> 7, o = t & 127;
    const float* a = agg + bd * HH;
    const float* w = Ws + o * 256;
    float acc = bsc[o];
    for (int h = 0; h < HH; ++h) acc += a[h] * w[h];
    ap[t] = acc;
}

// ---------------------------------------------------------------------------
// K5: proj through Wk: kp[r][d*H+o] = sum_h hid[r][d*H+h] * W_score[o*256+128+h]
// 8 rows per block.
// ---------------------------------------------------------------------------
__global__ void k_proj(const float* __restrict__ hid, const float* __restrict__ Ws,
                       float* __restrict__ kp, int nrows) {
    int r0 = blockIdx.x * 8;
    __shared__ float sh[8][DH];
    int t = threadIdx.x;
    for (int x = t; x < 8 * DH; x += 256) {
        int rr = x >> 9, j = x & 511;
        int r = r0 + rr;
        sh[rr][j] = (r < nrows) ? hid[r * DH + j] : 0.f;
    }
    __syncthreads();
    for (int j = t; j < DH; j += 256) {
        int d = j >> 7, o = j & 127;
        const float* w = Ws + o * 256 + HH;
        float acc[8] = {0.f,0.f,0.f,0.f,0.f,0.f,0.f,0.f};
        for (int h = 0; h < HH; ++h) {
            float wv = w[h];
#pragma unroll
            for (int rr = 0; rr < 8; ++rr) acc[rr] += sh[rr][d * HH + h] * wv;
        }
#pragma unroll
        for (int rr = 0; rr < 8; ++rr) {
            int r = r0 + rr;
            if (r < nrows) kp[r * DH + j] = acc[rr];
        }
    }
}

// ---------------------------------------------------------------------------
// K6: demand_score[b][d][s] = sum_o w[o]*relu(ap[bd][o] + kp[b*S+s][d*H+o])
// ---------------------------------------------------------------------------
__global__ void k_score(const float* __restrict__ ap, const float* __restrict__ kp,
                        const float* __restrict__ wsc, float* __restrict__ out) {
    int t = blockIdx.x * 256 + threadIdx.x;
    if (t >= BB * DD * SS) return;
    int b = t / (DD * SS);
    int rem = t - b * (DD * SS);
    int d = rem / SS, s = rem - d * SS;
    const float* a = ap + (b * DD + d) * HH;
    const float* k = kp + (b * SS + s) * DH + d * HH;
    float acc = 0.f;
    for (int o = 0; o < HH; ++o) acc += wsc[o] * fmaxf(a[o] + k[o], 0.f);
    out[t] = acc;
}

// ---------------------------------------------------------------------------
// K7: demand_score_candidate[b][d][i] = sum_o w[o]*relu(ap[bd][o] + cp[i][d*H+o])
// Block: fixed d, tile of 64 i, all 32 b.  LDS padded to 129 to kill bank
// conflicts (8 distinct rows per wave read).
// ---------------------------------------------------------------------------
#define ITILE 64
#define LPAD 129
__global__ void k_cand_score(const float* __restrict__ ap, const float* __restrict__ cp,
                             const float* __restrict__ wsc, float* __restrict__ out) {
    const int ntiles = (NI + ITILE - 1) / ITILE;
    int d = blockIdx.x / ntiles;
    int tile = blockIdx.x - d * ntiles;
    int i0 = tile * ITILE;
    __shared__ float sap[BB * LPAD];
    __shared__ float scp[ITILE * LPAD];
    __shared__ float sw[HH];
    int t = threadIdx.x;
    if (t < HH) sw[t] = wsc[t];
    for (int x = t; x < BB * HH; x += 256) {
        int b = x >> 7, o = x & 127;
        sap[b * LPAD + o] = ap[(b * DD + d) * HH + o];
    }
    for (int x = t; x < ITILE * HH; x += 256) {
        int il = x >> 7, o = x & 127;
        int i = i0 + il;
        scp[il * LPAD + o] = (i < NI) ? cp[i * DH + d * HH + o] : 0.f;
    }
    __syncthreads();
    int b = t >> 3, g = t & 7;
    float acc[8] = {0.f,0.f,0.f,0.f,0.f,0.f,0.f,0.f};
    const float* arow = sap + b * LPAD;
    for (int o = 0; o < HH; ++o) {
        float a = arow[o];
        float w = sw[o];
#pragma unroll
        for (int kk = 0; kk < 8; ++kk) {
            int il = kk * 8 + g;
            acc[kk] += w * fmaxf(a + scp[il * LPAD + o], 0.f);
        }
    }
#pragma unroll
    for (int kk = 0; kk < 8; ++kk) {
        int i = i0 + kk * 8 + g;
        if (i < NI) out[b * (DD * NI) + d * NI + i] = acc[kk];
    }
}

// ---------------------------------------------------------------------------
extern "C" void kernel_launch(void* const* d_in, const int* in_sizes, int n_in,
                              void* d_out, int out_size, void* d_ws, size_t ws_size,
                              hipStream_t stream) {
    const int*   inp  = (const int*)d_in[0];     // (B,S)
    const int*   cand = (const int*)d_in[1];     // (I,)
    const float* et   = (const float*)d_in[2];   // (N_CAT,E)
    const float* Wd   = (const float*)d_in[3];   // (D*H,E)
    const float* Ws   = (const float*)d_in[4];   // (H,2H)
    const float* bsc  = (const float*)d_in[5];   // (H,)
    const float* wsc  = (const float*)d_in[6];   // (H,)

    float* out = (float*)d_out;
    // output layout (flat, return order):
    float* o_ds   = out;                  // (B,D,S)    6400
    float* o_dsc  = out + 6400;           // (B,D,I)    640000
    float* o_emb  = out + 646400;         // (B,S,E)    204800
    float* o_cemb = out + 851200;         // (I,E)      640000
    float* o_loss = out + 1491200;        // scalar

    // workspace layout (floats); total ~27.2 MB
    float* ws = (float*)d_ws;
    float* hidden  = ws;                      // 1600*512
    float* chidden = ws + 819200;             // 5000*512
    float* agg     = ws + 3379200;            // 16384
    float* ap      = ws + 3395584;            // 16384
    float* cp      = ws + 3411968;            // 5000*512
    float* kp      = ws + 5971968;            // 1600*512

    const int ROWS_IN = BB * SS;   // 1600
    // K1: input hidden + emb out
    hipLaunchKernelGGL(k_hidden, dim3((ROWS_IN + 7) / 8), dim3(256), 0, stream,
                       inp, et, Wd, o_emb, hidden, ROWS_IN);
    // K1b: candidate hidden + cand_emb out
    hipLaunchKernelGGL(k_hidden, dim3((NI + 7) / 8), dim3(256), 0, stream,
                       cand, et, Wd, o_cemb, chidden, NI);
    // K2: logsumexp over s
    hipLaunchKernelGGL(k_agg, dim3(16384 / 256), dim3(256), 0, stream, hidden, agg);
    // K3: loss
    hipLaunchKernelGGL(k_loss, dim3(1), dim3(128), 0, stream, agg, o_loss);
    // K4: agg_proj
    hipLaunchKernelGGL(k_aggproj, dim3(16384 / 256), dim3(256), 0, stream, agg, Ws, bsc, ap);
    // K5: key_proj (input rows), cand_proj (candidate rows)
    hipLaunchKernelGGL(k_proj, dim3((ROWS_IN + 7) / 8), dim3(256), 0, stream, hidden, Ws, kp, ROWS_IN);
    hipLaunchKernelGGL(k_proj, dim3((NI + 7) / 8), dim3(256), 0, stream, chidden, Ws, cp, NI);
    // K6: demand_score
    hipLaunchKernelGGL(k_score, dim3((BB * DD * SS + 255) / 256), dim3(256), 0, stream,
                       ap, kp, wsc, o_ds);
    // K7: demand_score_candidate
    const int ntiles = (NI + ITILE - 1) / ITILE;
    hipLaunchKernelGGL(k_cand_score, dim3(DD * ntiles), dim3(256), 0, stream,
                       ap, cp, wsc, o_dsc);
}